// Round 1
// baseline (632.897 us; speedup 1.0000x reference)
//
#include <hip/hip_runtime.h>

// Problem constants
#define BATCH 2048
#define KIN   64
#define KOUT  64
#define NPT   256                 // block FFT length
#define NF    129                 // half-spectrum bins
#define PLANE_STRIDE (NF * KIN)   // 8256 floats per batch row in X planes
#define XPLANE ((size_t)BATCH * PLANE_STRIDE)   // 16,908,288 floats
#define WPLANE (NF * KIN * KOUT)                // 528,384 floats

// ---------------------------------------------------------------------------
// Stockham radix-2 FFT, 256 points, one wave (64 lanes), LDS ping-pong.
// Data starts in A; after 8 stages result is back in A (even swap count).
// C = sign * 2*pi/256. Caller must __syncthreads() before calling.
// ---------------------------------------------------------------------------
__device__ __forceinline__ void fft_stages(float2* A, float2* B, int lane, float C) {
  float2* src = A;
  float2* dst = B;
#pragma unroll
  for (int stage = 0; stage < 8; ++stage) {
    const int m = 1 << stage;
#pragma unroll
    for (int it = 0; it < 2; ++it) {
      const int t  = lane + (it << 6);      // butterfly index 0..127
      const int jm = t & ~(m - 1);          // j*m
      float2 c0 = src[t];
      float2 c1 = src[t + 128];
      float ang = C * (float)jm;            // sign*2pi*j/(2l) == sign*2pi*jm/256
      float sw, cw;
      __sincosf(ang, &sw, &cw);
      float dx = c0.x - c1.x, dy = c0.y - c1.y;
      dst[t + jm]     = make_float2(c0.x + c1.x, c0.y + c1.y);
      dst[t + jm + m] = make_float2(cw * dx - sw * dy, cw * dy + sw * dx);
    }
    __syncthreads();
    float2* tmp = src; src = dst; dst = tmp;
  }
}

// ---------------------------------------------------------------------------
// k0: transpose W (KOUT,KIN,NF) -> per-frequency planes [f][j][i]
// ---------------------------------------------------------------------------
__global__ __launch_bounds__(256) void k0_wtrans(const float* __restrict__ Wre,
                                                 const float* __restrict__ Wim,
                                                 float* __restrict__ Wtr,
                                                 float* __restrict__ Wti) {
  int n = blockIdx.x * 256 + threadIdx.x;   // over NF*KIN*KOUT
  if (n >= WPLANE) return;
  int f   = n >> 12;        // /4096
  int rem = n & 4095;
  int j   = rem >> 6;
  int i   = rem & 63;
  size_t src = ((size_t)(i * KIN + j)) * NF + f;
  Wtr[n] = Wre[src];
  Wti[n] = Wim[src];
}

// ---------------------------------------------------------------------------
// k1: rfft of each (b,j) block of 256 real samples -> Xr/Xi[b][f][j], f=0..128
// One wave per block, 4 blocks per workgroup.
// ---------------------------------------------------------------------------
__global__ __launch_bounds__(256) void k1_rfft(const float* __restrict__ x,
                                               float* __restrict__ Xr,
                                               float* __restrict__ Xi) {
  __shared__ float2 buf[4][2][NPT];         // 16 KB
  const int wave = threadIdx.x >> 6;
  const int lane = threadIdx.x & 63;
  const int idx  = blockIdx.x * 4 + wave;   // flat b*KIN + j
  const float* xin = x + (size_t)idx * NPT;

  float2* A  = buf[wave][0];
  float2* Bb = buf[wave][1];

  float4 v = reinterpret_cast<const float4*>(xin)[lane];
  A[lane * 4 + 0] = make_float2(v.x, 0.f);
  A[lane * 4 + 1] = make_float2(v.y, 0.f);
  A[lane * 4 + 2] = make_float2(v.z, 0.f);
  A[lane * 4 + 3] = make_float2(v.w, 0.f);
  __syncthreads();

  fft_stages(A, Bb, lane, -6.283185307179586f / 256.f);

  const int b = idx >> 6, j = idx & 63;
  float* pr = Xr + (size_t)b * PLANE_STRIDE + j;
  float* pi = Xi + (size_t)b * PLANE_STRIDE + j;
  for (int f = lane; f < NF; f += 64) {
    float2 z = A[f];
    pr[(size_t)f * KIN] = z.x;
    pi[(size_t)f * KIN] = z.y;
  }
}

// ---------------------------------------------------------------------------
// k2: per-frequency complex GEMM  O[b][i] = sum_j X[b][j] * conj(W[i][j])
// Tile: 64 rows x all 64 i. In-place over X planes (tile fully staged first).
// LDS pad 68 floats: (68*4)%16==0 so float4 reads stay aligned; banks spread.
// ---------------------------------------------------------------------------
__global__ __launch_bounds__(256) void k2_cgemm(float* __restrict__ Xr,
                                                float* __restrict__ Xi,
                                                const float* __restrict__ Wtr,
                                                const float* __restrict__ Wti) {
  __shared__ __align__(16) float Xlr[64 * 68];
  __shared__ __align__(16) float Xli[64 * 68];
  __shared__ __align__(16) float Wlr[64 * 68];
  __shared__ __align__(16) float Wli[64 * 68];

  const int f  = blockIdx.y;        // 0..128
  const int b0 = blockIdx.x * 64;   // row tile
  const int t  = threadIdx.x;

  const float* wpr = Wtr + (size_t)f * (KIN * KOUT);
  const float* wpi = Wti + (size_t)f * (KIN * KOUT);
#pragma unroll
  for (int it = 0; it < 16; ++it) {
    int n = it * 256 + t;
    int j = n >> 6, i = n & 63;
    Wlr[j * 68 + i] = wpr[n];
    Wli[j * 68 + i] = wpi[n];
  }
#pragma unroll
  for (int it = 0; it < 16; ++it) {
    int n = it * 256 + t;
    int r = n >> 6, j = n & 63;
    size_t g = (size_t)(b0 + r) * PLANE_STRIDE + (size_t)f * KIN + j;
    Xlr[j * 68 + r] = Xr[g];
    Xli[j * 68 + r] = Xi[g];
  }
  __syncthreads();

  const int tx = t & 15, ty = t >> 4;
  const int i0 = tx * 4, r0 = ty * 4;
  float aR[4][4] = {};
  float aI[4][4] = {};

#pragma unroll 4
  for (int j = 0; j < 64; ++j) {
    float4 xr = *reinterpret_cast<const float4*>(&Xlr[j * 68 + r0]);
    float4 xi = *reinterpret_cast<const float4*>(&Xli[j * 68 + r0]);
    float4 wr = *reinterpret_cast<const float4*>(&Wlr[j * 68 + i0]);
    float4 wi = *reinterpret_cast<const float4*>(&Wli[j * 68 + i0]);
    float xra[4] = {xr.x, xr.y, xr.z, xr.w};
    float xia[4] = {xi.x, xi.y, xi.z, xi.w};
    float wra[4] = {wr.x, wr.y, wr.z, wr.w};
    float wia[4] = {wi.x, wi.y, wi.z, wi.w};
#pragma unroll
    for (int a = 0; a < 4; ++a)
#pragma unroll
      for (int c = 0; c < 4; ++c) {
        // X * conj(W): re += xr*wr + xi*wi ; im += xi*wr - xr*wi
        aR[a][c] += xra[a] * wra[c] + xia[a] * wia[c];
        aI[a][c] += xia[a] * wra[c] - xra[a] * wia[c];
      }
  }

#pragma unroll
  for (int a = 0; a < 4; ++a) {
    size_t g = (size_t)(b0 + r0 + a) * PLANE_STRIDE + (size_t)f * KIN + i0;
    *reinterpret_cast<float4*>(&Xr[g]) = make_float4(aR[a][0], aR[a][1], aR[a][2], aR[a][3]);
    *reinterpret_cast<float4*>(&Xi[g]) = make_float4(aI[a][0], aI[a][1], aI[a][2], aI[a][3]);
  }
}

// ---------------------------------------------------------------------------
// k3: rebuild full conjugate-symmetric spectrum for (b,i), inverse FFT,
// write real part (scaled 1/256) coalesced.
// ---------------------------------------------------------------------------
__global__ __launch_bounds__(256) void k3_irfft(const float* __restrict__ Or,
                                                const float* __restrict__ Oi,
                                                float* __restrict__ out) {
  __shared__ float2 buf[4][2][NPT];
  const int wave = threadIdx.x >> 6;
  const int lane = threadIdx.x & 63;
  const int idx  = blockIdx.x * 4 + wave;   // flat b*KOUT + i
  const int b = idx >> 6, i = idx & 63;

  float2* A  = buf[wave][0];
  float2* Bb = buf[wave][1];

  const float* pr = Or + (size_t)b * PLANE_STRIDE + i;
  const float* pi = Oi + (size_t)b * PLANE_STRIDE + i;
  for (int f = lane; f < NF; f += 64) {
    float re = pr[(size_t)f * KIN];
    float im = pi[(size_t)f * KIN];
    A[f] = make_float2(re, im);
    if (f >= 1 && f <= 127) A[NPT - f] = make_float2(re, -im);
  }
  __syncthreads();

  fft_stages(A, Bb, lane, 6.283185307179586f / 256.f);

  const float s = 1.0f / 256.f;
  float4 o;
  o.x = A[lane * 4 + 0].x * s;
  o.y = A[lane * 4 + 1].x * s;
  o.z = A[lane * 4 + 2].x * s;
  o.w = A[lane * 4 + 3].x * s;
  reinterpret_cast<float4*>(out + (size_t)idx * NPT)[lane] = o;
}

// ---------------------------------------------------------------------------
extern "C" void kernel_launch(void* const* d_in, const int* in_sizes, int n_in,
                              void* d_out, int out_size, void* d_ws, size_t ws_size,
                              hipStream_t stream) {
  const float* x   = (const float*)d_in[0];
  const float* Wre = (const float*)d_in[1];
  const float* Wim = (const float*)d_in[2];
  float* out = (float*)d_out;
  float* ws  = (float*)d_ws;

  float* Xr  = ws;
  float* Xi  = ws + XPLANE;
  float* Wtr = ws + 2 * XPLANE;
  float* Wti = Wtr + WPLANE;
  // total ws use: (2*XPLANE + 2*WPLANE)*4 bytes ~= 133 MB

  hipLaunchKernelGGL(k0_wtrans, dim3((WPLANE + 255) / 256), dim3(256), 0, stream,
                     Wre, Wim, Wtr, Wti);
  hipLaunchKernelGGL(k1_rfft, dim3(BATCH * KIN / 4), dim3(256), 0, stream,
                     x, Xr, Xi);
  hipLaunchKernelGGL(k2_cgemm, dim3(BATCH / 64, NF), dim3(256), 0, stream,
                     Xr, Xi, Wtr, Wti);
  hipLaunchKernelGGL(k3_irfft, dim3(BATCH * KOUT / 4), dim3(256), 0, stream,
                     Xr, Xi, out);
}

// Round 2
// 462.876 us; speedup vs baseline: 1.3673x; 1.3673x over previous
//
#include <hip/hip_runtime.h>

// Problem constants
#define BATCH 2048
#define KIN   64
#define KOUT  64
#define NPT   256                        // block FFT length
#define NF    129                        // half-spectrum bins
#define FSTRIDE (BATCH * KIN)            // 131072 floats per f-plane row
#define XPLANE ((size_t)NF * FSTRIDE)    // 16,908,288 floats per re/im plane
#define WPLANE (NF * KIN * KOUT)         // 528,384 floats
#define NFP 133                          // padded staging row stride (gcd(5,32)=1)

// wave-level LDS fence: wave64 lockstep + in-order DS pipe makes this a valid
// substitute for __syncthreads() on wave-private LDS regions.
#define WAVE_SYNC() __asm__ volatile("s_waitcnt lgkmcnt(0)" ::: "memory")

// LDS index pad for FFT buffers: spreads power-of-2 strides across banks.
__device__ __forceinline__ int PHI(int i) { return i + (i >> 5); }

// ---------------------------------------------------------------------------
// Radix-4 Stockham FFT, 256 points, one wave (64 lanes), wave-private LDS
// ping-pong buffers (264 float2 each, PHI-indexed). 4 stages, result in A.
// Derived by composing two verified radix-2 Stockham stages:
//   d[t+3jm]    =  (s0+s2) + (s1+s3)
//   d[t+3jm+m]  = W(jm)  * [(s0-s2) + sign*i*(s1-s3)]
//   d[t+3jm+2m] = W(2jm) * [(s0+s2) - (s1+s3)]
//   d[t+3jm+3m] = W(3jm) * [(s0-s2) - sign*i*(s1-s3)]
// with W(x) = exp(sign*2*pi*i*x/256), verified against DFT-4 at N=4.
// ---------------------------------------------------------------------------
template<int SIGN>
__device__ __forceinline__ void fft256_r4(float2* A, float2* B, int lane) {
  float2* src = A;
  float2* dst = B;
  const float C = SIGN * (6.28318530717958647692f / 256.f);
#pragma unroll
  for (int st = 0; st < 4; ++st) {
    const int m  = 1 << (2 * st);
    const int t  = lane;
    const int jm = t & ~(m - 1);
    float2 s0 = src[PHI(t)];
    float2 s1 = src[PHI(t + 64)];
    float2 s2 = src[PHI(t + 128)];
    float2 s3 = src[PHI(t + 192)];
    float sw, cw;
    __sincosf(C * (float)jm, &sw, &cw);
    float c2 = cw * cw - sw * sw, s2w = 2.f * cw * sw;       // W(2jm)
    float c3 = c2 * cw - s2w * sw, s3w = c2 * sw + s2w * cw; // W(3jm)
    float apcx = s0.x + s2.x, apcy = s0.y + s2.y;
    float amcx = s0.x - s2.x, amcy = s0.y - s2.y;
    float bpdx = s1.x + s3.x, bpdy = s1.y + s3.y;
    float bmdx = s1.x - s3.x, bmdy = s1.y - s3.y;
    // sign*i*(bx+i by) = sign*(-by + i bx)
    float sbx = (SIGN < 0) ? bmdy : -bmdy;
    float sby = (SIGN < 0) ? -bmdx : bmdx;
    float t1x = amcx + sbx, t1y = amcy + sby;
    float t3x = amcx - sbx, t3y = amcy - sby;
    float t2x = apcx - bpdx, t2y = apcy - bpdy;
    const int base = t + 3 * jm;
    dst[PHI(base)]         = make_float2(apcx + bpdx, apcy + bpdy);
    dst[PHI(base + m)]     = make_float2(cw * t1x - sw * t1y, cw * t1y + sw * t1x);
    dst[PHI(base + 2 * m)] = make_float2(c2 * t2x - s2w * t2y, c2 * t2y + s2w * t2x);
    dst[PHI(base + 3 * m)] = make_float2(c3 * t3x - s3w * t3y, c3 * t3y + s3w * t3x);
    WAVE_SYNC();
    float2* tmp = src; src = dst; dst = tmp;
  }
}

// ---------------------------------------------------------------------------
// k0: tiled transpose W[i][j][f] -> Wtr/Wti[f][j*64+i], both sides coalesced.
// ---------------------------------------------------------------------------
__global__ __launch_bounds__(256) void k0_wtrans(const float* __restrict__ Wre,
                                                 const float* __restrict__ Wim,
                                                 float* __restrict__ Wtr,
                                                 float* __restrict__ Wti) {
  __shared__ float T[32][33];
  const int f0 = blockIdx.y * 32;       // 0,32,64,96,128
  const int d0 = blockIdx.x * 32;       // dest inner index d = j*64+i
  const int t  = threadIdx.x;
  const int a  = t & 31, g = t >> 5;
#pragma unroll
  for (int pl = 0; pl < 2; ++pl) {
    const float* src = pl ? Wim : Wre;
    float* dst = pl ? Wti : Wtr;
    if (pl) __syncthreads();
#pragma unroll
    for (int it = 0; it < 4; ++it) {
      int dl = g + it * 8;
      int d  = d0 + dl;
      int s  = (d & 63) * 64 + (d >> 6);   // source row i*64+j
      int f  = f0 + a;
      if (f < NF) T[dl][a] = src[(size_t)s * NF + f];
    }
    __syncthreads();
#pragma unroll
    for (int it = 0; it < 4; ++it) {
      int fl = g + it * 8;
      int f  = f0 + fl;
      if (f < NF) dst[(size_t)f * (KIN * KOUT) + d0 + a] = T[a][fl];
    }
  }
}

// ---------------------------------------------------------------------------
// k1: rfft of 32 (b,j) blocks per workgroup (one b, half the j's), fused
// LDS-staged transpose, coalesced writes to f-major planes Xtr/Xti[f][b*64+j].
// ---------------------------------------------------------------------------
__global__ __launch_bounds__(256) void k1_rfft(const float* __restrict__ x,
                                               float* __restrict__ Xtr,
                                               float* __restrict__ Xti) {
  __shared__ float2 fbuf[4][2][264];    // 16.9 KB
  __shared__ float Sr[32 * NFP];        // 17 KB
  __shared__ float Si[32 * NFP];        // 17 KB
  const int wave = threadIdx.x >> 6, lane = threadIdx.x & 63;
  const int b = blockIdx.x >> 1, h = blockIdx.x & 1;
  float2* A  = fbuf[wave][0];
  float2* Bp = fbuf[wave][1];
#pragma unroll
  for (int rr = 0; rr < 8; ++rr) {
    const int jt  = rr * 4 + wave;                  // 0..31
    const int idx = b * 64 + h * 32 + jt;
    float4 v = reinterpret_cast<const float4*>(x + (size_t)idx * NPT)[lane];
    A[PHI(4 * lane + 0)] = make_float2(v.x, 0.f);
    A[PHI(4 * lane + 1)] = make_float2(v.y, 0.f);
    A[PHI(4 * lane + 2)] = make_float2(v.z, 0.f);
    A[PHI(4 * lane + 3)] = make_float2(v.w, 0.f);
    WAVE_SYNC();
    fft256_r4<-1>(A, Bp, lane);
    float2 z0 = A[PHI(lane)];
    float2 z1 = A[PHI(lane + 64)];
    Sr[jt * NFP + lane]      = z0.x;  Si[jt * NFP + lane]      = z0.y;
    Sr[jt * NFP + lane + 64] = z1.x;  Si[jt * NFP + lane + 64] = z1.y;
    if (lane == 0) {
      float2 z2 = A[PHI(128)];
      Sr[jt * NFP + 128] = z2.x;  Si[jt * NFP + 128] = z2.y;
    }
    WAVE_SYNC();
  }
  __syncthreads();
  // cooperative coalesced write-out: 32 consecutive idx per f
  const int c = threadIdx.x & 31;
  const size_t baseidx = (size_t)b * 64 + h * 32 + c;
#pragma unroll
  for (int it = 0; it < 17; ++it) {
    int f = (threadIdx.x >> 5) + it * 8;
    if (f < NF) {
      Xtr[(size_t)f * FSTRIDE + baseidx] = Sr[c * NFP + f];
      Xti[(size_t)f * FSTRIDE + baseidx] = Si[c * NFP + f];
    }
  }
}

// ---------------------------------------------------------------------------
// k2: per-frequency complex GEMM  O[b][i] = sum_j X[b][j] * conj(W[i][j])
// f-major planes: all global access contiguous. In-place over X (tile fully
// staged to LDS before any write; blocks touch disjoint ranges).
// ---------------------------------------------------------------------------
__global__ __launch_bounds__(256) void k2_cgemm(float* __restrict__ Xr,
                                                float* __restrict__ Xi,
                                                const float* __restrict__ Wtr,
                                                const float* __restrict__ Wti) {
  __shared__ __align__(16) float Xlr[64 * 68];
  __shared__ __align__(16) float Xli[64 * 68];
  __shared__ __align__(16) float Wlr[64 * 68];
  __shared__ __align__(16) float Wli[64 * 68];

  const int f  = blockIdx.y;
  const int b0 = blockIdx.x * 64;
  const int t  = threadIdx.x;
  const size_t xbase = (size_t)f * FSTRIDE + (size_t)b0 * 64;
  const float* wpr = Wtr + (size_t)f * (KIN * KOUT);
  const float* wpi = Wti + (size_t)f * (KIN * KOUT);

  // W tile: [j][i], vector load + vector store (already in [j][i] layout)
#pragma unroll
  for (int it = 0; it < 4; ++it) {
    int n4 = (it * 256 + t) * 4;
    int j = n4 >> 6, i0 = n4 & 63;
    float4 wr = *reinterpret_cast<const float4*>(wpr + n4);
    float4 wi = *reinterpret_cast<const float4*>(wpi + n4);
    *reinterpret_cast<float4*>(&Wlr[j * 68 + i0]) = wr;
    *reinterpret_cast<float4*>(&Wli[j * 68 + i0]) = wi;
  }
  // X tile: vector load rows, transposed scalar stores -> [j][r]
#pragma unroll
  for (int it = 0; it < 4; ++it) {
    int n4 = (it * 256 + t) * 4;
    int r = n4 >> 6, j0 = n4 & 63;
    float4 xr = *reinterpret_cast<const float4*>(Xr + xbase + n4);
    float4 xi = *reinterpret_cast<const float4*>(Xi + xbase + n4);
    Xlr[(j0 + 0) * 68 + r] = xr.x; Xlr[(j0 + 1) * 68 + r] = xr.y;
    Xlr[(j0 + 2) * 68 + r] = xr.z; Xlr[(j0 + 3) * 68 + r] = xr.w;
    Xli[(j0 + 0) * 68 + r] = xi.x; Xli[(j0 + 1) * 68 + r] = xi.y;
    Xli[(j0 + 2) * 68 + r] = xi.z; Xli[(j0 + 3) * 68 + r] = xi.w;
  }
  __syncthreads();

  const int tx = t & 15, ty = t >> 4;
  const int i0 = tx * 4, r0 = ty * 4;
  float aR[4][4] = {};
  float aI[4][4] = {};

#pragma unroll 4
  for (int j = 0; j < 64; ++j) {
    float4 xr = *reinterpret_cast<const float4*>(&Xlr[j * 68 + r0]);
    float4 xi = *reinterpret_cast<const float4*>(&Xli[j * 68 + r0]);
    float4 wr = *reinterpret_cast<const float4*>(&Wlr[j * 68 + i0]);
    float4 wi = *reinterpret_cast<const float4*>(&Wli[j * 68 + i0]);
    float xra[4] = {xr.x, xr.y, xr.z, xr.w};
    float xia[4] = {xi.x, xi.y, xi.z, xi.w};
    float wra[4] = {wr.x, wr.y, wr.z, wr.w};
    float wia[4] = {wi.x, wi.y, wi.z, wi.w};
#pragma unroll
    for (int a = 0; a < 4; ++a)
#pragma unroll
      for (int c = 0; c < 4; ++c) {
        // X * conj(W): re += xr*wr + xi*wi ; im += xi*wr - xr*wi
        aR[a][c] += xra[a] * wra[c] + xia[a] * wia[c];
        aI[a][c] += xia[a] * wra[c] - xra[a] * wia[c];
      }
  }

#pragma unroll
  for (int a = 0; a < 4; ++a) {
    size_t g = xbase + (size_t)(r0 + a) * 64 + i0;
    *reinterpret_cast<float4*>(&Xr[g]) = make_float4(aR[a][0], aR[a][1], aR[a][2], aR[a][3]);
    *reinterpret_cast<float4*>(&Xi[g]) = make_float4(aI[a][0], aI[a][1], aI[a][2], aI[a][3]);
  }
}

// ---------------------------------------------------------------------------
// k3: coalesced gather from f-major O planes into LDS staging, conjugate-
// symmetric spectrum rebuild, inverse radix-4 FFT, coalesced real output.
// ---------------------------------------------------------------------------
__global__ __launch_bounds__(256) void k3_irfft(const float* __restrict__ Or,
                                                const float* __restrict__ Oi,
                                                float* __restrict__ out) {
  __shared__ float2 fbuf[4][2][264];
  __shared__ float Sr[32 * NFP];
  __shared__ float Si[32 * NFP];
  const int wave = threadIdx.x >> 6, lane = threadIdx.x & 63;
  const int b = blockIdx.x >> 1, h = blockIdx.x & 1;
  const int c = threadIdx.x & 31;
  const size_t baseidx = (size_t)b * 64 + h * 32 + c;
#pragma unroll
  for (int it = 0; it < 17; ++it) {
    int f = (threadIdx.x >> 5) + it * 8;
    if (f < NF) {
      Sr[c * NFP + f] = Or[(size_t)f * FSTRIDE + baseidx];
      Si[c * NFP + f] = Oi[(size_t)f * FSTRIDE + baseidx];
    }
  }
  __syncthreads();
  float2* A  = fbuf[wave][0];
  float2* Bp = fbuf[wave][1];
#pragma unroll
  for (int rr = 0; rr < 8; ++rr) {
    const int it8 = rr * 4 + wave;                  // ĩ 0..31
    float re0 = Sr[it8 * NFP + lane],      im0 = Si[it8 * NFP + lane];
    float re1 = Sr[it8 * NFP + lane + 64], im1 = Si[it8 * NFP + lane + 64];
    A[PHI(lane)]      = make_float2(re0, im0);
    A[PHI(lane + 64)] = make_float2(re1, im1);
    if (lane) A[PHI(256 - lane)] = make_float2(re0, -im0);   // f = 1..63
    A[PHI(192 - lane)] = make_float2(re1, -im1);             // f = 64..127
    if (lane == 0)
      A[PHI(128)] = make_float2(Sr[it8 * NFP + 128], Si[it8 * NFP + 128]);
    WAVE_SYNC();
    fft256_r4<1>(A, Bp, lane);
    const float s = 1.0f / 256.f;
    float4 o;
    o.x = A[PHI(4 * lane + 0)].x * s;
    o.y = A[PHI(4 * lane + 1)].x * s;
    o.z = A[PHI(4 * lane + 2)].x * s;
    o.w = A[PHI(4 * lane + 3)].x * s;
    const int idx = b * 64 + h * 32 + it8;
    reinterpret_cast<float4*>(out + (size_t)idx * NPT)[lane] = o;
    WAVE_SYNC();
  }
}

// ---------------------------------------------------------------------------
extern "C" void kernel_launch(void* const* d_in, const int* in_sizes, int n_in,
                              void* d_out, int out_size, void* d_ws, size_t ws_size,
                              hipStream_t stream) {
  const float* x   = (const float*)d_in[0];
  const float* Wre = (const float*)d_in[1];
  const float* Wim = (const float*)d_in[2];
  float* out = (float*)d_out;
  float* ws  = (float*)d_ws;

  float* Xr  = ws;                      // f-major plane [f][b*64+j]
  float* Xi  = ws + XPLANE;
  float* Wtr = ws + 2 * XPLANE;         // [f][j*64+i]
  float* Wti = Wtr + WPLANE;
  // ws use: (2*XPLANE + 2*WPLANE)*4 B ~= 139.5 MB (same as round 1)

  hipLaunchKernelGGL(k0_wtrans, dim3(128, 5), dim3(256), 0, stream,
                     Wre, Wim, Wtr, Wti);
  hipLaunchKernelGGL(k1_rfft, dim3(BATCH * 2), dim3(256), 0, stream,
                     x, Xr, Xi);
  hipLaunchKernelGGL(k2_cgemm, dim3(BATCH / 64, NF), dim3(256), 0, stream,
                     Xr, Xi, Wtr, Wti);
  hipLaunchKernelGGL(k3_irfft, dim3(BATCH * 2), dim3(256), 0, stream,
                     Xr, Xi, out);
}